// Round 8
// baseline (811.209 us; speedup 1.0000x reference)
//
#include <hip/hip_runtime.h>

#define M_ROWS 32768
#define DIM    512
#define KCB    8192
#define BM     128
#define BN     128
#define NSTEP  16           // K-steps of 32
#define NSLAB  128          // 64-col slabs per row

typedef _Float16 f16x8  __attribute__((ext_vector_type(8)));
typedef float    f32x16 __attribute__((ext_vector_type(16)));
typedef unsigned long long u64;

#define AS1(p) ((const __attribute__((address_space(1))) void*)(p))
#define AS3(p) ((__attribute__((address_space(3))) void*)(p))

// ---- pack fp16 hi-plane into 32x32x16 fragment order, 128-row tiles --------
// 16B unit u: l=u&63, f=(u>>6)&7 (mb=f>>1, ks=f&1), t=(u>>9)&15, rb=u>>13
// holds row rb*128+mb*32+(l&31), k = t*32 + ks*16 + (l>>5)*8 .. +8
__global__ void __launch_bounds__(256)
vq_fragpack(const float* __restrict__ x, _Float16* __restrict__ dst,
            float scale, int nfr) {
    int u = blockIdx.x * 256 + threadIdx.x;
    if (u >= nfr) return;
    int l  = u & 63;
    int f  = (u >> 6) & 7;
    int t  = (u >> 9) & 15;
    int rb = u >> 13;
    int row = rb * 128 + (f >> 1) * 32 + (l & 31);
    int k   = t * 32 + (f & 1) * 16 + (l >> 5) * 8;
    const float* src = x + (size_t)row * DIM + k;
    float4 v0 = *(const float4*)src;
    float4 v1 = *(const float4*)(src + 4);
    f16x8 h = { (_Float16)(v0.x*scale), (_Float16)(v0.y*scale),
                (_Float16)(v0.z*scale), (_Float16)(v0.w*scale),
                (_Float16)(v1.x*scale), (_Float16)(v1.y*scale),
                (_Float16)(v1.z*scale), (_Float16)(v1.w*scale) };
    *(f16x8*)((char*)dst + (size_t)u * 16) = h;
}

// ---------------------------------------------------------------- row norms
__global__ void __launch_bounds__(256) vq_rownorm(const float* __restrict__ z,
                                                  float* __restrict__ A) {
    int row  = blockIdx.x * 4 + (threadIdx.x >> 6);
    int lane = threadIdx.x & 63;
    const float* zr = z + (size_t)row * DIM;
    float4 a = *(const float4*)(zr + lane * 4);
    float4 b = *(const float4*)(zr + 256 + lane * 4);
    float s = a.x*a.x + a.y*a.y + a.z*a.z + a.w*a.w
            + b.x*b.x + b.y*b.y + b.z*b.z + b.w*b.w;
    #pragma unroll
    for (int off = 32; off > 0; off >>= 1) s += __shfl_down(s, off, 64);
    if (lane == 0) A[row] = s;
}

// ---- m97-style 128x128 / 4-wave / 2-phase dbuf MFMA GEMM + top-2 select ----
__global__ void __launch_bounds__(256, 3)
vq_gemm(const _Float16* __restrict__ zf, const _Float16* __restrict__ ef,
        const float* __restrict__ Anorm, u64* __restrict__ cand) {
    __shared__ char lds[32768];            // 2 x (A 8KB | B 8KB)
    const int tid  = threadIdx.x;
    const int lane = tid & 63;
    const int wid  = tid >> 6;
    const int wm   = wid >> 1;             // 0..1 -> 64-row half
    const int wn   = wid & 1;              // 0..1 -> 64-col half

    // XCD-aware swizzle: each XCD owns 8 consecutive col-panels (B L2-hot)
    int bid = (int)blockIdx.x;
    int xcd = bid & 7, s = bid >> 3;
    const int cbk = (xcd << 3) + (s >> 8); // 0..63
    const int rb  = s & 255;               // 0..255

    const char* zsrc = (const char*)zf + ((size_t)rb  << 17);  // 16*8KB
    const char* esrc = (const char*)ef + ((size_t)cbk << 17);

    f32x16 acc[2][2];
    #pragma unroll
    for (int mi = 0; mi < 2; ++mi)
        #pragma unroll
        for (int nj = 0; nj < 2; ++nj) acc[mi][nj] = (f32x16)0.0f;

#define STAGE(t) do {                                                         \
    char* dst_ = lds + (((t) & 1) << 14);                                     \
    _Pragma("unroll")                                                         \
    for (int j = 0; j < 4; ++j) {                                             \
        int n_ = (wid << 2) | j;                                              \
        const char* src_ = (n_ < 8)                                           \
            ? zsrc + (((size_t)(t) << 13) + ((size_t)n_ << 10)) + (lane << 4) \
            : esrc + (((size_t)(t) << 13) + ((size_t)(n_ - 8) << 10)) + (lane << 4); \
        __builtin_amdgcn_global_load_lds(AS1(src_), AS3(dst_ + (n_ << 10)), 16, 0, 0); \
    }                                                                         \
} while (0)

#define COMPUTE(t) do {                                                       \
    const char* bufA_ = lds + (((t) & 1) << 14);                              \
    const char* bufB_ = bufA_ + 8192;                                         \
    _Pragma("unroll")                                                         \
    for (int ks = 0; ks < 2; ++ks) {                                          \
        f16x8 a0 = *(const f16x8*)(bufA_ + (((wm * 2 + 0) * 2 + ks) << 10) + (lane << 4)); \
        f16x8 a1 = *(const f16x8*)(bufA_ + (((wm * 2 + 1) * 2 + ks) << 10) + (lane << 4)); \
        f16x8 b0 = *(const f16x8*)(bufB_ + (((wn * 2 + 0) * 2 + ks) << 10) + (lane << 4)); \
        f16x8 b1 = *(const f16x8*)(bufB_ + (((wn * 2 + 1) * 2 + ks) << 10) + (lane << 4)); \
        acc[0][0] = __builtin_amdgcn_mfma_f32_32x32x16_f16(a0, b0, acc[0][0], 0, 0, 0); \
        acc[0][1] = __builtin_amdgcn_mfma_f32_32x32x16_f16(a0, b1, acc[0][1], 0, 0, 0); \
        acc[1][0] = __builtin_amdgcn_mfma_f32_32x32x16_f16(a1, b0, acc[1][0], 0, 0, 0); \
        acc[1][1] = __builtin_amdgcn_mfma_f32_32x32x16_f16(a1, b1, acc[1][1], 0, 0, 0); \
    }                                                                         \
} while (0)

    STAGE(0);
    __syncthreads();
    #pragma unroll 1
    for (int t = 0; t < NSTEP; ++t) {
        if (t + 1 < NSTEP) STAGE(t + 1);
        COMPUTE(t);
        __syncthreads();
    }

    // epilogue: d = A - acc/2048, top-2 per row over wave's 64 cols
    float* As = (float*)lds;
    if (tid < BM) As[tid] = Anorm[rb * BM + tid];
    __syncthreads();

    const int slab = (cbk << 1) | wn;      // 0..127
    #pragma unroll
    for (int mi = 0; mi < 2; ++mi) {
        #pragma unroll
        for (int r = 0; r < 16; ++r) {
            int rit   = (r & 3) + ((r >> 2) << 3) + ((lane >> 5) << 2);
            int row_l = wm * 64 + mi * 32 + rit;
            float Arow = As[row_l];
            u64 b1v = ~0ull, b2v = ~0ull;
            #pragma unroll
            for (int nj = 0; nj < 2; ++nj) {
                float d = Arow - acc[mi][nj][r] * (1.0f / 2048.0f);
                int col = (cbk << 7) + (wn << 6) + (nj << 5) + (lane & 31);
                u64 p = ((u64)__float_as_uint(d) << 32) | (unsigned)col;
                if (p < b1v) { b2v = b1v; b1v = p; } else if (p < b2v) b2v = p;
            }
            #pragma unroll
            for (int mk = 1; mk < 32; mk <<= 1) {
                u64 o1 = __shfl_xor(b1v, mk);
                u64 o2 = __shfl_xor(b2v, mk);
                u64 lo = b1v < o1 ? b1v : o1;
                u64 hi = b1v < o1 ? o1 : b1v;
                u64 so = b2v < o2 ? b2v : o2;
                b1v = lo; b2v = hi < so ? hi : so;
            }
            if ((lane & 31) == 0) {
                size_t base = (size_t)(rb * BM + row_l) * (2 * NSLAB)
                            + (size_t)(slab << 1);
                cand[base]     = b1v;
                cand[base + 1] = b2v;
            }
        }
    }
}

// ------- refine (exact fp32 chain, round-1 semantics) + gather + loss ------
__global__ void __launch_bounds__(256)
vq_refine_gather(const float* __restrict__ z, const float* __restrict__ cb,
                 const float* __restrict__ Anorm, const u64* __restrict__ cand,
                 float* __restrict__ outQ, float* __restrict__ outIdx,
                 double* __restrict__ lossRow) {
    __shared__ float zs[4][DIM];
    __shared__ int   sc[4][128];
    int w = threadIdx.x >> 6, lane = threadIdx.x & 63;
    int row = blockIdx.x * 4 + w;

    const float* zr = z + (size_t)row * DIM;
    *(float4*)&zs[w][lane * 4]       = *(const float4*)(zr + lane * 4);
    *(float4*)&zs[w][256 + lane * 4] = *(const float4*)(zr + 256 + lane * 4);

    const u64* cr = cand + (size_t)row * (2 * NSLAB);
    u64 c[4];
    #pragma unroll
    for (int k = 0; k < 4; ++k) c[k] = cr[lane * 4 + k];
    u64 mn = c[0];
    #pragma unroll
    for (int k = 1; k < 4; ++k) if (c[k] < mn) mn = c[k];
    #pragma unroll
    for (int m = 32; m > 0; m >>= 1) { u64 o = __shfl_xor(mn, m); if (o < mn) mn = o; }
    float minD = __uint_as_float((unsigned)(mn >> 32));
    float thr = minD + 2e-4f;
    u64 below = ((u64)1 << lane) - 1;
    int base = 0;
    #pragma unroll
    for (int k = 0; k < 4; ++k) {
        bool sk = __uint_as_float((unsigned)(c[k] >> 32)) <= thr;
        u64 mk = __ballot(sk);
        if (sk) {
            int slot = base + __popcll(mk & below);
            if (slot < 128) sc[w][slot] = (int)(unsigned)c[k];
        }
        base += __popcll(mk);
    }
    int ns = base < 128 ? base : 128;
    __syncthreads();

    float Arow = Anorm[row];
    u64 best = ~0ull;
    for (int j = lane; j < ns; j += 64) {
        int col = sc[w][j];
        const float* e = cb + (size_t)col * DIM;
        float acc2 = 0.0f;
        for (int k = 0; k < DIM; ++k) acc2 = fmaf(zs[w][k], e[k], acc2);
        float d = Arow - 2.0f * acc2;
        u64 p = ((u64)__float_as_uint(d) << 32) | (unsigned)col;
        if (p < best) best = p;
    }
    #pragma unroll
    for (int m = 32; m > 0; m >>= 1) { u64 o = __shfl_xor(best, m); if (o < best) best = o; }
    best = __shfl(best, 0);
    int bi = (int)(unsigned)best;

    const float* q = cb + (size_t)bi * DIM;
    float* o = outQ + (size_t)row * DIM;
    double ls = 0.0;
    #pragma unroll
    for (int j = 0; j < 2; ++j) {
        int off = j * 256 + lane * 4;
        float4 qv = *(const float4*)(q + off);
        float4 zv = *(const float4*)&zs[w][off];
        float t0 = qv.x - zv.x, t1 = qv.y - zv.y;
        float t2 = qv.z - zv.z, t3 = qv.w - zv.w;
        float4 ov = { zv.x + t0, zv.y + t1, zv.z + t2, zv.w + t3 };
        *(float4*)(o + off) = ov;
        ls += (double)t0 * t0 + (double)t1 * t1
            + (double)t2 * t2 + (double)t3 * t3;
    }
    #pragma unroll
    for (int off = 32; off > 0; off >>= 1) ls += __shfl_down(ls, off, 64);
    if (lane == 0) { lossRow[row] = ls; outIdx[row] = (float)bi; }
}

__global__ void __launch_bounds__(256)
vq_loss_final(const double* __restrict__ lossRow, float* __restrict__ outLoss) {
    __shared__ double sm[256];
    double s = 0.0;
    for (int i = threadIdx.x; i < M_ROWS; i += 256) s += lossRow[i];
    sm[threadIdx.x] = s;
    __syncthreads();
    for (int st = 128; st > 0; st >>= 1) {
        if (threadIdx.x < st) sm[threadIdx.x] += sm[threadIdx.x + st];
        __syncthreads();
    }
    if (threadIdx.x == 0)
        outLoss[0] = (float)(1.25 * sm[0] / (double)((size_t)M_ROWS * DIM));
}

extern "C" void kernel_launch(void* const* d_in, const int* in_sizes, int n_in,
                              void* d_out, int out_size, void* d_ws, size_t ws_size,
                              hipStream_t stream) {
    const float* z  = (const float*)d_in[0];
    const float* cb = (const float*)d_in[1];

    float* out     = (float*)d_out;
    float* outQ    = out;
    float* outIdx  = out + (size_t)M_ROWS * DIM;
    float* outLoss = out + (size_t)M_ROWS * DIM + M_ROWS;

    // fragment-ordered z lives in d_out scratch (overwritten later by gather)
    _Float16* zfrag = (_Float16*)d_out;                    // 32 MB

    char* ws = (char*)d_ws;
    float*  A       = (float*)ws;            ws += (size_t)M_ROWS * 4;
    double* lossRow = (double*)ws;           ws += (size_t)M_ROWS * 8;
    _Float16* efrag = (_Float16*)ws;         ws += (size_t)KCB * DIM * 2;    // 8 MB
    u64*    cand    = (u64*)ws;              // 32768*256*8 = 67 MB

    int nfr_z = M_ROWS * DIM / 8;            // 2097152
    int nfr_e = KCB * DIM / 8;               // 524288
    hipLaunchKernelGGL(vq_fragpack, dim3(nfr_z / 256), dim3(256), 0, stream,
                       z, zfrag, 1.0f, nfr_z);
    hipLaunchKernelGGL(vq_fragpack, dim3(nfr_e / 256), dim3(256), 0, stream,
                       cb, efrag, 4096.0f, nfr_e);
    hipLaunchKernelGGL(vq_rownorm, dim3(M_ROWS / 4), dim3(256), 0, stream, z, A);
    hipLaunchKernelGGL(vq_gemm, dim3((M_ROWS / BM) * (KCB / BN)), dim3(256),
                       0, stream, zfrag, efrag, A, cand);
    hipLaunchKernelGGL(vq_refine_gather, dim3(M_ROWS / 4), dim3(256), 0, stream,
                       z, cb, A, cand, outQ, outIdx, lossRow);
    hipLaunchKernelGGL(vq_loss_final, dim3(1), dim3(256), 0, stream, lossRow, outLoss);
}

// Round 9
// 539.422 us; speedup vs baseline: 1.5038x; 1.5038x over previous
//
#include <hip/hip_runtime.h>

#define M_ROWS 32768
#define DIM    512
#define KCB    8192
#define BM     256
#define BN     256
#define NSLAB  128          // 64-col slabs per row

typedef _Float16 f16x8 __attribute__((ext_vector_type(8)));
typedef float    f32x4 __attribute__((ext_vector_type(4)));
typedef unsigned long long u64;

#define AS1(p) ((const __attribute__((address_space(1))) void*)(p))
#define AS3(p) ((__attribute__((address_space(3))) void*)(p))

// -------- pack fp16 hi-plane into MFMA 16x16x32 fragment order --------------
// frag unit u: lane l = u&63, g = (u>>6)&15, s = (u>>10)&15, rb = u>>14
// holds (row = rb*256 + g*16 + (l&15), k = s*32 + (l>>4)*8 .. +8)
__global__ void __launch_bounds__(256)
vq_fragpack(const float* __restrict__ x, _Float16* __restrict__ dst,
            float scale, int nfr) {
    int u = blockIdx.x * 256 + threadIdx.x;
    if (u >= nfr) return;
    int l  = u & 63;
    int g  = (u >> 6) & 15;
    int s  = (u >> 10) & 15;
    int rb = u >> 14;
    int row = rb * 256 + g * 16 + (l & 15);
    int k   = s * 32 + (l >> 4) * 8;
    const float* src = x + (size_t)row * DIM + k;
    float4 v0 = *(const float4*)src;
    float4 v1 = *(const float4*)(src + 4);
    f16x8 h = { (_Float16)(v0.x*scale), (_Float16)(v0.y*scale),
                (_Float16)(v0.z*scale), (_Float16)(v0.w*scale),
                (_Float16)(v1.x*scale), (_Float16)(v1.y*scale),
                (_Float16)(v1.z*scale), (_Float16)(v1.w*scale) };
    *(f16x8*)((char*)dst + (size_t)u * 16) = h;
}

// ---------------------------------------------------------------- row norms
__global__ void __launch_bounds__(256) vq_rownorm(const float* __restrict__ z,
                                                  float* __restrict__ A) {
    int row  = blockIdx.x * 4 + (threadIdx.x >> 6);
    int lane = threadIdx.x & 63;
    const float* zr = z + (size_t)row * DIM;
    float4 a = *(const float4*)(zr + lane * 4);
    float4 b = *(const float4*)(zr + 256 + lane * 4);
    float s = a.x*a.x + a.y*a.y + a.z*a.z + a.w*a.w
            + b.x*b.x + b.y*b.y + b.z*b.z + b.w*b.w;
    #pragma unroll
    for (int off = 32; off > 0; off >>= 1) s += __shfl_down(s, off, 64);
    if (lane == 0) A[row] = s;
}

// ------- counted-vmcnt 4-buffer pipelined f16 MFMA GEMM + top-2 select ------
// r4 schedule, fully unrolled K-loop (literal t -> LDS imm offsets, folded
// staging addresses) + u32-key epilogue.
__global__ void __launch_bounds__(512, 2)
vq_gemm(const _Float16* __restrict__ zf, const _Float16* __restrict__ ef,
        const float* __restrict__ Anorm, u64* __restrict__ cand) {
    extern __shared__ char lds[];          // 4 buffers x (A 16KB | B 16KB)
    const int tid  = threadIdx.x;
    const int lane = tid & 63;
    const int wid  = tid >> 6;
    const int wm   = wid >> 2;             // 0..1 -> 128-row half
    const int wn   = wid & 3;              // 0..3 -> 64-col quarter
    const int rb   = (int)blockIdx.x >> 5;
    const int cbk  = (int)blockIdx.x & 31;
    const char* zsrc = (const char*)zf + ((size_t)rb  << 18);  // 16 steps * 16KB
    const char* esrc = (const char*)ef + ((size_t)cbk << 18);

    f32x4 acc[8][4];
    #pragma unroll
    for (int m = 0; m < 8; ++m)
        #pragma unroll
        for (int n = 0; n < 4; ++n) acc[m][n] = (f32x4)0.0f;

#define STAGE(t) do {                                                         \
    char* dst_ = lds + (((t) & 3) << 15);                                     \
    _Pragma("unroll")                                                         \
    for (int j = 0; j < 4; ++j) {                                             \
        int n2 = (wid << 2) | j;                                              \
        const char* src_ = (n2 < 16)                                          \
            ? zsrc + (((t) << 14) + (n2 << 10)) + (lane << 4)                 \
            : esrc + (((t) << 14) + ((n2 - 16) << 10)) + (lane << 4);         \
        __builtin_amdgcn_global_load_lds(AS1(src_), AS3(dst_ + (n2 << 10)), 16, 0, 0); \
    }                                                                         \
} while (0)

#define COMPUTE(t) do {                                                       \
    const char* bufA_ = lds + (((t) & 3) << 15);                              \
    const char* bufB_ = bufA_ + 16384;                                        \
    f16x8 af[8];                                                              \
    _Pragma("unroll")                                                         \
    for (int m = 0; m < 8; ++m)                                               \
        af[m] = *(const f16x8*)(bufA_ + (((wm << 3) | m) << 10) + (lane << 4)); \
    f16x8 b0 = *(const f16x8*)(bufB_ + (((wn << 2) | 0) << 10) + (lane << 4)); \
    f16x8 b1 = *(const f16x8*)(bufB_ + (((wn << 2) | 1) << 10) + (lane << 4)); \
    __builtin_amdgcn_s_setprio(1);                                            \
    _Pragma("unroll")                                                         \
    for (int m = 0; m < 8; ++m) {                                             \
        acc[m][0] = __builtin_amdgcn_mfma_f32_16x16x32_f16(af[m], b0, acc[m][0], 0, 0, 0); \
        acc[m][1] = __builtin_amdgcn_mfma_f32_16x16x32_f16(af[m], b1, acc[m][1], 0, 0, 0); \
    }                                                                         \
    __builtin_amdgcn_s_setprio(0);                                            \
    f16x8 b2 = *(const f16x8*)(bufB_ + (((wn << 2) | 2) << 10) + (lane << 4)); \
    f16x8 b3 = *(const f16x8*)(bufB_ + (((wn << 2) | 3) << 10) + (lane << 4)); \
    __builtin_amdgcn_s_setprio(1);                                            \
    _Pragma("unroll")                                                         \
    for (int m = 0; m < 8; ++m) {                                             \
        acc[m][2] = __builtin_amdgcn_mfma_f32_16x16x32_f16(af[m], b2, acc[m][2], 0, 0, 0); \
        acc[m][3] = __builtin_amdgcn_mfma_f32_16x16x32_f16(af[m], b3, acc[m][3], 0, 0, 0); \
    }                                                                         \
    __builtin_amdgcn_s_setprio(0);                                            \
} while (0)

#define STEP(t) do {                                                          \
    STAGE((t) + 3);                                                           \
    COMPUTE(t);                                                               \
    asm volatile("s_waitcnt vmcnt(8) lgkmcnt(0)" ::: "memory");               \
    asm volatile("s_barrier" ::: "memory");                                   \
    __builtin_amdgcn_sched_barrier(0);                                        \
} while (0)

    // prologue: 3 buffers in flight, retire buf0
    STAGE(0); STAGE(1); STAGE(2);
    asm volatile("s_waitcnt vmcnt(8)" ::: "memory");
    asm volatile("s_barrier" ::: "memory");
    __builtin_amdgcn_sched_barrier(0);

    STEP(0);  STEP(1);  STEP(2);  STEP(3);  STEP(4);  STEP(5);  STEP(6);
    STEP(7);  STEP(8);  STEP(9);  STEP(10); STEP(11); STEP(12);

    COMPUTE(13);
    asm volatile("s_waitcnt vmcnt(4) lgkmcnt(0)" ::: "memory");      // retire 14
    asm volatile("s_barrier" ::: "memory");
    __builtin_amdgcn_sched_barrier(0);
    COMPUTE(14);
    asm volatile("s_waitcnt vmcnt(0) lgkmcnt(0)" ::: "memory");      // retire 15
    asm volatile("s_barrier" ::: "memory");
    __builtin_amdgcn_sched_barrier(0);
    COMPUTE(15);
    __syncthreads();

    // epilogue: d = A - acc/2048, top-2 per row over wave's 64 cols.
    // u32 key = (sat16(d_bits - (A_bits-8192)) << 16) | col — exact order
    // (fp32 bit pattern monotone; |2C| <= 0.072 << 8192 ulp margin 0.25-0.5).
    float* As = (float*)lds;
    if (tid < BM) As[tid] = Anorm[rb * BM + tid];
    __syncthreads();

    #pragma unroll
    for (int m = 0; m < 8; ++m) {
        #pragma unroll
        for (int rg = 0; rg < 4; ++rg) {
            int row_l = (wm << 7) + (m << 4) + ((lane >> 4) << 2) + rg;
            float Arow = As[row_l];
            unsigned abase = __float_as_uint(Arow) - 8192u;
            unsigned k1 = 0xFFFFFFFFu, k2 = 0xFFFFFFFFu;
            #pragma unroll
            for (int nj = 0; nj < 4; ++nj) {
                float d = Arow - acc[m][nj][rg] * (1.0f / 2048.0f);
                unsigned io = __float_as_uint(d) - abase;
                io = io > 65535u ? 65535u : io;
                unsigned col = (cbk << 8) + (wn << 6) + (nj << 4) + (lane & 15);
                unsigned key = (io << 16) | col;
                if (key < k1) { k2 = k1; k1 = key; }
                else if (key < k2) k2 = key;
            }
            #pragma unroll
            for (int mk = 1; mk < 16; mk <<= 1) {
                unsigned o1 = (unsigned)__shfl_xor((int)k1, mk);
                unsigned o2 = (unsigned)__shfl_xor((int)k2, mk);
                unsigned lo = k1 < o1 ? k1 : o1;
                unsigned hi = k1 < o1 ? o1 : k1;
                unsigned so = k2 < o2 ? k2 : o2;
                k1 = lo;
                k2 = hi < so ? hi : so;
            }
            if ((lane & 15) == 0) {
                size_t base = (size_t)(rb * BM + row_l) * (2 * NSLAB)
                            + (size_t)(((cbk << 2) | wn) << 1);
                cand[base]     = ((u64)(abase + (k1 >> 16)) << 32) | (u64)(k1 & 0xFFFFu);
                cand[base + 1] = ((u64)(abase + (k2 >> 16)) << 32) | (u64)(k2 & 0xFFFFu);
            }
        }
    }
}

// ------- refine (exact fp32 chain, round-1 semantics) + gather + loss ------
__global__ void __launch_bounds__(256)
vq_refine_gather(const float* __restrict__ z, const float* __restrict__ cb,
                 const float* __restrict__ Anorm, const u64* __restrict__ cand,
                 float* __restrict__ outQ, float* __restrict__ outIdx,
                 double* __restrict__ lossRow) {
    __shared__ float zs[4][DIM];
    __shared__ int   sc[4][128];
    int w = threadIdx.x >> 6, lane = threadIdx.x & 63;
    int row = blockIdx.x * 4 + w;

    const float* zr = z + (size_t)row * DIM;
    *(float4*)&zs[w][lane * 4]       = *(const float4*)(zr + lane * 4);
    *(float4*)&zs[w][256 + lane * 4] = *(const float4*)(zr + 256 + lane * 4);

    const u64* cr = cand + (size_t)row * (2 * NSLAB);
    u64 c[4];
    #pragma unroll
    for (int k = 0; k < 4; ++k) c[k] = cr[lane * 4 + k];
    u64 mn = c[0];
    #pragma unroll
    for (int k = 1; k < 4; ++k) if (c[k] < mn) mn = c[k];
    #pragma unroll
    for (int m = 32; m > 0; m >>= 1) { u64 o = __shfl_xor(mn, m); if (o < mn) mn = o; }
    float minD = __uint_as_float((unsigned)(mn >> 32));
    float thr = minD + 2e-4f;
    u64 below = ((u64)1 << lane) - 1;
    int base = 0;
    #pragma unroll
    for (int k = 0; k < 4; ++k) {
        bool sk = __uint_as_float((unsigned)(c[k] >> 32)) <= thr;
        u64 mk = __ballot(sk);
        if (sk) {
            int slot = base + __popcll(mk & below);
            if (slot < 128) sc[w][slot] = (int)(unsigned)c[k];
        }
        base += __popcll(mk);
    }
    int ns = base < 128 ? base : 128;
    __syncthreads();

    float Arow = Anorm[row];
    u64 best = ~0ull;
    for (int j = lane; j < ns; j += 64) {
        int col = sc[w][j];
        const float* e = cb + (size_t)col * DIM;
        float acc2 = 0.0f;
        for (int k = 0; k < DIM; ++k) acc2 = fmaf(zs[w][k], e[k], acc2);
        float d = Arow - 2.0f * acc2;
        u64 p = ((u64)__float_as_uint(d) << 32) | (unsigned)col;
        if (p < best) best = p;
    }
    #pragma unroll
    for (int m = 32; m > 0; m >>= 1) { u64 o = __shfl_xor(best, m); if (o < best) best = o; }
    best = __shfl(best, 0);
    int bi = (int)(unsigned)best;

    const float* q = cb + (size_t)bi * DIM;
    float* o = outQ + (size_t)row * DIM;
    double ls = 0.0;
    #pragma unroll
    for (int j = 0; j < 2; ++j) {
        int off = j * 256 + lane * 4;
        float4 qv = *(const float4*)(q + off);
        float4 zv = *(const float4*)&zs[w][off];
        float t0 = qv.x - zv.x, t1 = qv.y - zv.y;
        float t2 = qv.z - zv.z, t3 = qv.w - zv.w;
        float4 ov = { zv.x + t0, zv.y + t1, zv.z + t2, zv.w + t3 };
        *(float4*)(o + off) = ov;
        ls += (double)t0 * t0 + (double)t1 * t1
            + (double)t2 * t2 + (double)t3 * t3;
    }
    #pragma unroll
    for (int off = 32; off > 0; off >>= 1) ls += __shfl_down(ls, off, 64);
    if (lane == 0) { lossRow[row] = ls; outIdx[row] = (float)bi; }
}

__global__ void __launch_bounds__(256)
vq_loss_final(const double* __restrict__ lossRow, float* __restrict__ outLoss) {
    __shared__ double sm[256];
    double s = 0.0;
    for (int i = threadIdx.x; i < M_ROWS; i += 256) s += lossRow[i];
    sm[threadIdx.x] = s;
    __syncthreads();
    for (int st = 128; st > 0; st >>= 1) {
        if (threadIdx.x < st) sm[threadIdx.x] += sm[threadIdx.x + st];
        __syncthreads();
    }
    if (threadIdx.x == 0)
        outLoss[0] = (float)(1.25 * sm[0] / (double)((size_t)M_ROWS * DIM));
}

extern "C" void kernel_launch(void* const* d_in, const int* in_sizes, int n_in,
                              void* d_out, int out_size, void* d_ws, size_t ws_size,
                              hipStream_t stream) {
    const float* z  = (const float*)d_in[0];
    const float* cb = (const float*)d_in[1];

    float* out     = (float*)d_out;
    float* outQ    = out;
    float* outIdx  = out + (size_t)M_ROWS * DIM;
    float* outLoss = out + (size_t)M_ROWS * DIM + M_ROWS;

    // fragment-ordered z lives in d_out scratch (overwritten later by gather)
    _Float16* zfrag = (_Float16*)d_out;                    // 32 MB

    char* ws = (char*)d_ws;
    float*  A       = (float*)ws;            ws += (size_t)M_ROWS * 4;
    double* lossRow = (double*)ws;           ws += (size_t)M_ROWS * 8;
    _Float16* efrag = (_Float16*)ws;         ws += (size_t)KCB * DIM * 2;    // 8 MB
    u64*    cand    = (u64*)ws;              // 32768*256*8 = 67 MB

    int nfr_z = M_ROWS * DIM / 8;            // 2097152
    int nfr_e = KCB * DIM / 8;               // 524288
    hipLaunchKernelGGL(vq_fragpack, dim3(nfr_z / 256), dim3(256), 0, stream,
                       z, zfrag, 1.0f, nfr_z);
    hipLaunchKernelGGL(vq_fragpack, dim3(nfr_e / 256), dim3(256), 0, stream,
                       cb, efrag, 4096.0f, nfr_e);
    hipLaunchKernelGGL(vq_rownorm, dim3(M_ROWS / 4), dim3(256), 0, stream, z, A);
    hipLaunchKernelGGL(vq_gemm, dim3((M_ROWS / BM) * (KCB / BN)), dim3(512),
                       131072, stream, zfrag, efrag, A, cand);
    hipLaunchKernelGGL(vq_refine_gather, dim3(M_ROWS / 4), dim3(256), 0, stream,
                       z, cb, A, cand, outQ, outIdx, lossRow);
    hipLaunchKernelGGL(vq_loss_final, dim3(1), dim3(256), 0, stream, lossRow, outLoss);
}